// Round 3
// baseline (272.633 us; speedup 1.0000x reference)
//
#include <hip/hip_runtime.h>
#include <stdint.h>
#include <stddef.h>

// Problem constants
#define BB 8
#define CC 16
#define DD 192
#define OCC 4
#define OHH 50
#define OWW 200

#define LDP 200   // padded LDS row stride in bf16 elements (192 + 8)
#define CH  24    // 8-element chunks per 192 row

typedef __attribute__((ext_vector_type(8))) short s8v;   // 8 bf16 = 16B (MFMA A/B frag)
typedef __attribute__((ext_vector_type(4))) short s4v;   // 4 bf16 = 8B
typedef __attribute__((ext_vector_type(4))) float f4v;   // 4 fp32
typedef __attribute__((ext_vector_type(4))) float f32x4; // MFMA C/D frag

__device__ __forceinline__ short rne_bf16(float f) {
  uint32_t u = __float_as_uint(f);
  u += 0x7fffu + ((u >> 16) & 1u);
  return (short)(u >> 16);
}
__device__ __forceinline__ float bf2f(short s) {
  return __uint_as_float(((uint32_t)(uint16_t)s) << 16);
}

// ---------------- prep_all: R-cvt | P-cvt | x-transpose | PT-transpose ----------------
// Block ranges (256 threads each):
//   [0, 9216)        cvt R   (n4 = 2359296)
//   [9216, 9816)     cvt P   (n4 = 153600)
//   [9816, 14424)    transpose_x  (128 outers x 36 tiles)
//   [14424, 17112)   transpose_pt (64 outers x 42 tiles)
#define PREP_R_BLK 9216
#define PREP_P_BLK 600
#define PREP_X_BLK 4608
#define PREP_PT_BLK 2688
#define PREP_TOTAL (PREP_R_BLK + PREP_P_BLK + PREP_X_BLK + PREP_PT_BLK)

__global__ __launch_bounds__(256) void prep_all(const float* __restrict__ R, short* __restrict__ Rb,
                                                const float* __restrict__ P, short* __restrict__ Pb,
                                                const float* __restrict__ x, short* __restrict__ XTb,
                                                const float* __restrict__ PT, short* __restrict__ PTTb) {
  __shared__ float tile[32][33];
  const int blk = blockIdx.x;
  const int tid = threadIdx.x;

  if (blk < PREP_R_BLK) {
    int idx = blk * 256 + tid;
    f4v v = *(const f4v*)(R + (size_t)idx * 4);
    s4v o;
    #pragma unroll
    for (int r = 0; r < 4; ++r) o[r] = rne_bf16(v[r]);
    *(s4v*)(Rb + (size_t)idx * 4) = o;
    return;
  }
  if (blk < PREP_R_BLK + PREP_P_BLK) {
    int idx = (blk - PREP_R_BLK) * 256 + tid;
    f4v v = *(const f4v*)(P + (size_t)idx * 4);
    s4v o;
    #pragma unroll
    for (int r = 0; r < 4; ++r) o[r] = rne_bf16(v[r]);
    *(s4v*)(Pb + (size_t)idx * 4) = o;
    return;
  }
  const int tx = tid & 31, ty = tid >> 5;
  if (blk < PREP_R_BLK + PREP_P_BLK + PREP_X_BLK) {
    int t = blk - (PREP_R_BLK + PREP_P_BLK);
    int outer = t / 36, rem = t % 36;
    int p0 = (rem / 6) * 32, q0 = (rem % 6) * 32;
    const float* src = x + (size_t)outer * DD * DD;
    for (int r = ty; r < 32; r += 8)
      tile[r][tx] = src[(size_t)(p0 + r) * DD + q0 + tx];
    __syncthreads();
    short* dst = XTb + (size_t)outer * DD * DD;
    for (int r = ty; r < 32; r += 8)
      dst[(size_t)(q0 + r) * DD + p0 + tx] = rne_bf16(tile[tx][r]);
    return;
  }
  {
    int t = blk - (PREP_R_BLK + PREP_P_BLK + PREP_X_BLK);
    int outer = t / 42, rem = t % 42;
    int q0 = (rem / 7) * 32, n0 = (rem % 7) * 32;
    const float* src = PT + (size_t)outer * DD * OWW;
    for (int r = ty; r < 32; r += 8)
      tile[r][tx] = (n0 + tx < OWW) ? src[(size_t)(q0 + r) * OWW + n0 + tx] : 0.f;
    __syncthreads();
    short* dst = PTTb + (size_t)outer * OWW * DD;
    for (int r = ty; r < 32; r += 8)
      if (n0 + r < OWW) dst[(size_t)(n0 + r) * DD + q0 + tx] = rne_bf16(tile[tx][r]);
  }
}

// ---------------- stage A ----------------
// y[b,i] = sum_j R[i,j] @ x[b,j] @ R[i,j]^T, split over jg halves.
// mm1: T^T[q][m] = sum_p XT[q][p] R[m][p]   (A = XT rows, B = R rows)
// mm2: y[m][n]   = sum_q T[m][q] R[n][q]    (A = T rows, B = R rows)
// Software pipeline: next j's R/XT tiles prefetched into registers during mm2,
// dumped to LDS after the top-of-loop barrier (post-barrier phase = LDS writes only).
// Output: ypart holds y^T (192x192 row-major [n][m]) per (jg,b,i).
__global__ __launch_bounds__(512, 2) void stageA(const short* __restrict__ Rb,
                                                 const short* __restrict__ XTb,
                                                 short* __restrict__ ypart) {
  __shared__ __align__(16) short ldsR[DD * LDP];
  __shared__ __align__(16) short lds2[DD * LDP];
  const int tid = threadIdx.x;
  const int bx = blockIdx.x;
  const int b = bx >> 5, i = (bx >> 1) & 15, jg = bx & 1;
  const int lane15 = tid & 15, quad = (tid & 63) >> 4;
  const int wid = tid >> 6;
  const int wm = wid & 3;   // 0..3 -> 3 tiles each (B-operand dim)
  const int wq = wid >> 2;  // 0..1 -> 6 tiles each (A-operand dim)

  // per-thread LDS staging offsets (9 chunks of 16B each)
  int ldsoff[9];
  #pragma unroll
  for (int it = 0; it < 9; ++it) {
    int c = tid + it * 512;
    ldsoff[it] = (c / CH) * LDP + (c % CH) * 8;
  }

  f32x4 acc_y[6][3];
  #pragma unroll
  for (int a = 0; a < 6; ++a)
    #pragma unroll
    for (int c = 0; c < 3; ++c) acc_y[a][c] = (f32x4){0.f, 0.f, 0.f, 0.f};

  // prefetch j = jg*8 + 0
  s8v preR[9], preX[9];
  {
    const short* sR = Rb + (size_t)(i * CC + jg * 8) * (DD * DD);
    const short* sX = XTb + (size_t)(b * CC + jg * 8) * (DD * DD);
    #pragma unroll
    for (int it = 0; it < 9; ++it) {
      preR[it] = *(const s8v*)(sR + (size_t)tid * 8 + (size_t)it * 4096);
      preX[it] = *(const s8v*)(sX + (size_t)tid * 8 + (size_t)it * 4096);
    }
  }

  for (int jj = 0; jj < 8; ++jj) {
    __syncthreads();  // previous iter done reading ldsR/lds2
    #pragma unroll
    for (int it = 0; it < 9; ++it) {
      *(s8v*)(&ldsR[ldsoff[it]]) = preR[it];
      *(s8v*)(&lds2[ldsoff[it]]) = preX[it];
    }
    __syncthreads();

    // mm1: T^T  (A = XT rows -> wq covers 6 q-tiles; B = R rows -> wm covers 3 m-tiles)
    f32x4 acc_t[6][3];
    #pragma unroll
    for (int a = 0; a < 6; ++a)
      #pragma unroll
      for (int c = 0; c < 3; ++c) acc_t[a][c] = (f32x4){0.f, 0.f, 0.f, 0.f};

    #pragma unroll
    for (int kc = 0; kc < 6; ++kc) {
      s8v af[6], bf[3];
      #pragma unroll
      for (int a = 0; a < 6; ++a)
        af[a] = *(const s8v*)(&lds2[((wq * 6 + a) * 16 + lane15) * LDP + kc * 32 + quad * 8]);
      #pragma unroll
      for (int c = 0; c < 3; ++c)
        bf[c] = *(const s8v*)(&ldsR[((wm * 3 + c) * 16 + lane15) * LDP + kc * 32 + quad * 8]);
      #pragma unroll
      for (int a = 0; a < 6; ++a)
        #pragma unroll
        for (int c = 0; c < 3; ++c)
          acc_t[a][c] = __builtin_amdgcn_mfma_f32_16x16x32_bf16(af[a], bf[c], acc_t[a][c], 0, 0, 0);
    }
    __syncthreads();  // done reading XT in lds2; overwrite with T

    // pack T[m][q] (bf16) into lds2
    #pragma unroll
    for (int a = 0; a < 6; ++a) {
      #pragma unroll
      for (int c = 0; c < 3; ++c) {
        s4v pk;
        #pragma unroll
        for (int r = 0; r < 4; ++r) pk[r] = rne_bf16(acc_t[a][c][r]);
        int m = (wm * 3 + c) * 16 + lane15;
        int q0 = (wq * 6 + a) * 16 + quad * 4;
        *(s4v*)(&lds2[m * LDP + q0]) = pk;
      }
    }
    __syncthreads();

    // prefetch next j (overlaps mm2; acc_t regs are dead here)
    if (jj < 7) {
      const short* sR = Rb + (size_t)(i * CC + jg * 8 + jj + 1) * (DD * DD);
      const short* sX = XTb + (size_t)(b * CC + jg * 8 + jj + 1) * (DD * DD);
      #pragma unroll
      for (int it = 0; it < 9; ++it) {
        preR[it] = *(const s8v*)(sR + (size_t)tid * 8 + (size_t)it * 4096);
        preX[it] = *(const s8v*)(sX + (size_t)tid * 8 + (size_t)it * 4096);
      }
    }

    // mm2: y[m][n] += T rows x R rows  (A = T -> wq covers 6 m-tiles; B = R -> wm covers 3 n-tiles)
    #pragma unroll
    for (int kc = 0; kc < 6; ++kc) {
      s8v af[6], bf[3];
      #pragma unroll
      for (int a = 0; a < 6; ++a)
        af[a] = *(const s8v*)(&lds2[((wq * 6 + a) * 16 + lane15) * LDP + kc * 32 + quad * 8]);
      #pragma unroll
      for (int c = 0; c < 3; ++c)
        bf[c] = *(const s8v*)(&ldsR[((wm * 3 + c) * 16 + lane15) * LDP + kc * 32 + quad * 8]);
      #pragma unroll
      for (int a = 0; a < 6; ++a)
        #pragma unroll
        for (int c = 0; c < 3; ++c)
          acc_y[a][c] = __builtin_amdgcn_mfma_f32_16x16x32_bf16(af[a], bf[c], acc_y[a][c], 0, 0, 0);
    }
  }

  // pack y^T [n][m] into lds2, then coalesced store
  __syncthreads();
  #pragma unroll
  for (int a = 0; a < 6; ++a) {
    #pragma unroll
    for (int c = 0; c < 3; ++c) {
      s4v pk;
      #pragma unroll
      for (int r = 0; r < 4; ++r) pk[r] = rne_bf16(acc_y[a][c][r]);
      int n = (wm * 3 + c) * 16 + lane15;       // B-row = n (col of y)
      int m0 = (wq * 6 + a) * 16 + quad * 4;    // A-row = m, 4 consecutive
      *(s4v*)(&lds2[n * LDP + m0]) = pk;
    }
  }
  __syncthreads();
  {
    short* dst = ypart + (size_t)(jg * (BB * CC) + b * CC + i) * (DD * DD);
    #pragma unroll
    for (int it = 0; it < 9; ++it) {
      int c = tid + it * 512;
      *(s8v*)(dst + (size_t)c * 8) = *(const s8v*)(&lds2[ldsoff[it]]);
    }
  }
}

// ---------------- fused stage B ----------------
// out[b,oc] = sum_j P[oc,j] @ y[b,j] @ PT[oc,j]
// Block = (b, oc, nh, jg): 4 j's per block, n-half of 100 cols, out acc in registers.
// Staging of y^T sums the two jg-halves of ypart inline (sum_y fused in).
// Epilogue: fp32 atomicAdd into d_out (memset to 0 beforehand) — reduce kernel fused out.
#define PROWS 64
#define PTROWS 128
__global__ __launch_bounds__(512, 2) void fusedB(const short* __restrict__ ypart,
                                                 const short* __restrict__ Pb,
                                                 const short* __restrict__ PTTb,
                                                 float* __restrict__ out) {
  __shared__ __align__(16) short ldsYT[DD * LDP];     // 76.8 KB; rows 0..63 reused for U
  __shared__ __align__(16) short ldsP[PROWS * LDP];   // 25.6 KB
  __shared__ __align__(16) short ldsPT[PTROWS * LDP]; // 51.2 KB
  const int tid = threadIdx.x;
  const int bx = blockIdx.x;
  const int jg = bx & 3, nh = (bx >> 2) & 1, oc = (bx >> 3) & 3, b = bx >> 5;
  const int lane15 = tid & 15, quad = (tid & 63) >> 4;
  const int wid = tid >> 6;
  // mm_b1 wave grid: 4 (q) x 2 (m)
  const int wq1 = wid >> 1, wm1 = wid & 1;
  // mm_b2 wave grid: 2 (m) x 4 (n)
  const int wm2 = wid & 1, wn2 = wid >> 1;

  f32x4 acc_o[2][2];
  #pragma unroll
  for (int a = 0; a < 2; ++a)
    #pragma unroll
    for (int e = 0; e < 2; ++e) acc_o[a][e] = (f32x4){0.f, 0.f, 0.f, 0.f};

  const s8v z = {0, 0, 0, 0, 0, 0, 0, 0};
  for (int jj = 0; jj < 4; ++jj) {
    const int j = jg * 4 + jj;
    __syncthreads();  // prev iter done reading U/ldsP/ldsPT
    {
      const short* p0 = ypart + (size_t)(b * CC + j) * (DD * DD);
      const short* p1 = p0 + (size_t)(BB * CC) * (DD * DD);
      for (int c = tid; c < DD * CH; c += 512) {
        s8v v0 = *(const s8v*)(p0 + (size_t)c * 8);
        s8v v1 = *(const s8v*)(p1 + (size_t)c * 8);
        s8v o;
        #pragma unroll
        for (int r = 0; r < 8; ++r) o[r] = rne_bf16(bf2f(v0[r]) + bf2f(v1[r]));
        int row = c / CH, col = c % CH;
        *(s8v*)(&ldsYT[row * LDP + col * 8]) = o;
      }
      const short* sp = Pb + (size_t)(oc * CC + j) * (OHH * DD);
      for (int c = tid; c < PROWS * CH; c += 512) {
        int row = c / CH, col = c % CH;
        *(s8v*)(&ldsP[row * LDP + col * 8]) =
            (c < OHH * CH) ? *(const s8v*)(sp + (size_t)c * 8) : z;
      }
      const short* st = PTTb + (size_t)(oc * CC + j) * (OWW * DD) + (size_t)nh * 100 * DD;
      for (int c = tid; c < PTROWS * CH; c += 512) {
        int row = c / CH, col = c % CH;
        *(s8v*)(&ldsPT[row * LDP + col * 8]) =
            (c < 100 * CH) ? *(const s8v*)(st + (size_t)c * 8) : z;
      }
    }
    __syncthreads();

    // mm_b1: U^T[q][m]; wq1 -> 3 q-tiles, wm1 -> 2 m-tiles
    f32x4 acc_t[3][2];
    #pragma unroll
    for (int a = 0; a < 3; ++a)
      #pragma unroll
      for (int c = 0; c < 2; ++c) acc_t[a][c] = (f32x4){0.f, 0.f, 0.f, 0.f};
    #pragma unroll
    for (int kc = 0; kc < 6; ++kc) {
      s8v af[3], bf[2];
      #pragma unroll
      for (int a = 0; a < 3; ++a)
        af[a] = *(const s8v*)(&ldsYT[((wq1 * 3 + a) * 16 + lane15) * LDP + kc * 32 + quad * 8]);
      #pragma unroll
      for (int c = 0; c < 2; ++c)
        bf[c] = *(const s8v*)(&ldsP[((wm1 * 2 + c) * 16 + lane15) * LDP + kc * 32 + quad * 8]);
      #pragma unroll
      for (int a = 0; a < 3; ++a)
        #pragma unroll
        for (int c = 0; c < 2; ++c)
          acc_t[a][c] = __builtin_amdgcn_mfma_f32_16x16x32_bf16(af[a], bf[c], acc_t[a][c], 0, 0, 0);
    }
    __syncthreads();  // yT fully consumed

    // pack U[m][q] into ldsYT rows 0..63
    #pragma unroll
    for (int a = 0; a < 3; ++a) {
      #pragma unroll
      for (int c = 0; c < 2; ++c) {
        s4v pk;
        #pragma unroll
        for (int r = 0; r < 4; ++r) pk[r] = rne_bf16(acc_t[a][c][r]);
        int m = (wm1 * 2 + c) * 16 + lane15;
        int q0 = (wq1 * 3 + a) * 16 + quad * 4;
        *(s4v*)(&ldsYT[m * LDP + q0]) = pk;
      }
    }
    __syncthreads();

    // mm_b2: out[m][n] += U rows x PT^T rows; wm2 -> 2 m-tiles, wn2 -> 2 n-tiles
    #pragma unroll
    for (int kc = 0; kc < 6; ++kc) {
      s8v af[2], bf[2];
      #pragma unroll
      for (int a = 0; a < 2; ++a)
        af[a] = *(const s8v*)(&ldsYT[((wm2 * 2 + a) * 16 + lane15) * LDP + kc * 32 + quad * 8]);
      #pragma unroll
      for (int e = 0; e < 2; ++e)
        bf[e] = *(const s8v*)(&ldsPT[((wn2 * 2 + e) * 16 + lane15) * LDP + kc * 32 + quad * 8]);
      #pragma unroll
      for (int a = 0; a < 2; ++a)
        #pragma unroll
        for (int e = 0; e < 2; ++e)
          acc_o[a][e] = __builtin_amdgcn_mfma_f32_16x16x32_bf16(af[a], bf[e], acc_o[a][e], 0, 0, 0);
    }
  }

  // atomicAdd fp32 into out[b,oc][m][nh*100 + n]
  float* dst = out + (size_t)(b * OCC + oc) * (OHH * OWW);
  #pragma unroll
  for (int a = 0; a < 2; ++a) {
    #pragma unroll
    for (int e = 0; e < 2; ++e) {
      int n = (wn2 * 2 + e) * 16 + lane15;
      if (n < 100) {
        #pragma unroll
        for (int r = 0; r < 4; ++r) {
          int m = (wm2 * 2 + a) * 16 + quad * 4 + r;
          if (m < OHH)
            atomicAdd(&dst[(size_t)m * OWW + nh * 100 + n], acc_o[a][e][r]);
        }
      }
    }
  }
}

// ---------------- launcher ----------------

extern "C" void kernel_launch(void* const* d_in, const int* in_sizes, int n_in,
                              void* d_out, int out_size, void* d_ws, size_t ws_size,
                              hipStream_t stream) {
  const float* x  = (const float*)d_in[0];
  const float* R  = (const float*)d_in[1];
  const float* P  = (const float*)d_in[2];
  const float* PT = (const float*)d_in[3];
  float* out = (float*)d_out;

  short* W = (short*)d_ws;
  const size_t nR   = (size_t)CC * CC * DD * DD;     // 9,437,184
  const size_t nX   = (size_t)BB * CC * DD * DD;     // 4,718,592
  const size_t nP   = (size_t)OCC * CC * OHH * DD;   // 614,400
  const size_t nPT  = (size_t)OCC * CC * OWW * DD;   // 2,457,600
  short* Rb    = W;
  short* XTb   = Rb + nR;
  short* Pb    = XTb + nX;
  short* PTTb  = Pb + nP;
  short* ypart = PTTb + nPT;                          // 2 * nX

  prep_all<<<PREP_TOTAL, 256, 0, stream>>>(R, Rb, P, Pb, x, XTb, PT, PTTb);
  stageA<<<BB * CC * 2, 512, 0, stream>>>(Rb, XTb, ypart);
  hipMemsetAsync(d_out, 0, (size_t)out_size * sizeof(float), stream);
  fusedB<<<BB * OCC * 2 * 4, 512, 0, stream>>>(ypart, Pb, PTTb, out);
}